// Round 5
// baseline (177.707 us; speedup 1.0000x reference)
//
#include <hip/hip_runtime.h>
#include <math.h>

#define F_IN 128
#define C 64
#define ELCAP 128
#define BCAP 64        // per-node in-edge bucket capacity (deg ~ 16 +- 4)
#define E2CAP 4096
#define E1CAP 32768
#define S0CAP 49152
#define S1CAP 4096

// cnt slots
#define I_EL 0
#define I_E2 1
#define I_E1 2
#define I_S0 3
#define I_S1 4
#define I_TEND 5

__device__ __forceinline__ void mark_append(int n, int* mark, int* map, int* list,
                                            int* cntp, int cap) {
  if (atomicCAS(&mark[n], 0, 1) == 0) {
    int idx = atomicAdd(cntp, 1);
    if (idx < cap) { list[idx] = n; map[n] = idx; }
  }
}

// ONE full edge pass: in-degree histogram + CSC bucket fill + node-incident edge detect
__global__ __launch_bounds__(256) void maskfill_kernel(const int* __restrict__ src,
    const int* __restrict__ dst, const int* __restrict__ node_p,
    int* __restrict__ deg, int* __restrict__ bucket, int* __restrict__ elist,
    int* __restrict__ cnt, int nE) {
  int e = blockIdx.x * 256 + threadIdx.x;
  if (e >= nE) return;
  int node = *node_p;
  int s = src[e], d = dst[e];
  int p = atomicAdd(&deg[d], 1);
  if (p < BCAP) bucket[(size_t)d * BCAP + p] = s;
  if (s == node || d == node) {
    int q = atomicAdd(&cnt[I_EL], 1);
    if (q < ELCAP) elist[q] = e;
  }
}

// single block: phase A = targets -> S1/S0; phase B = expand T rows -> e2, mark S1/S0
__global__ __launch_bounds__(1024) void frontier12_kernel(const int* __restrict__ src,
    const int* __restrict__ dst, const int* __restrict__ node_p,
    const int* __restrict__ elist, const int* __restrict__ deg,
    const int* __restrict__ bucket, int* __restrict__ mark0, int* __restrict__ mark1,
    int* __restrict__ map0, int* __restrict__ map1, int* __restrict__ s0list,
    int* __restrict__ s1list, int* __restrict__ e2s, int* __restrict__ e2d,
    int* __restrict__ cnt) {
  __shared__ int tend_s;
  int t = threadIdx.x;
  int n = cnt[I_EL]; if (n > ELCAP) n = ELCAP;
  int node = *node_p;
  for (int i = t; i < n; i += 1024) {
    int e = elist[i];
    int s = src[e], d = dst[e];
    int tgt = (s == node) ? d : s;
    mark_append(tgt, mark1, map1, s1list, &cnt[I_S1], S1CAP);
    mark_append(tgt, mark0, map0, s0list, &cnt[I_S0], S0CAP);
  }
  __syncthreads();
  if (t == 0) {
    int te = cnt[I_S1]; if (te > S1CAP) te = S1CAP;
    tend_s = te; cnt[I_TEND] = te;
  }
  __syncthreads();
  int tend = tend_s;
  int wid = t >> 6, lane = t & 63;
  for (int r = wid; r < tend; r += 16) {
    int v = s1list[r];
    int dg = deg[v]; if (dg > BCAP) dg = BCAP;
    const int* row = &bucket[(size_t)v * BCAP];
    for (int j = lane; j < dg; j += 64) {
      int s = row[j];
      int p = atomicAdd(&cnt[I_E2], 1);
      if (p < E2CAP) { e2s[p] = s; e2d[p] = v; }
      mark_append(s, mark1, map1, s1list, &cnt[I_S1], S1CAP);
      mark_append(s, mark0, map0, s0list, &cnt[I_S0], S0CAP);
    }
  }
}

// expand all S1 rows -> e1 pairs, mark srcs into S0
__global__ __launch_bounds__(256) void frontier3_kernel(const int* __restrict__ deg,
    const int* __restrict__ bucket, const int* __restrict__ s1list,
    int* __restrict__ mark0, int* __restrict__ map0, int* __restrict__ s0list,
    int* __restrict__ e1s, int* __restrict__ e1d, int* __restrict__ cnt) {
  int s1c = cnt[I_S1]; if (s1c > S1CAP) s1c = S1CAP;
  for (int r = blockIdx.x; r < s1c; r += gridDim.x) {
    int v = s1list[r];
    int dg = deg[v]; if (dg > BCAP) dg = BCAP;
    const int* row = &bucket[(size_t)v * BCAP];
    for (int j = threadIdx.x; j < dg; j += 256) {
      int s = row[j];
      int p = atomicAdd(&cnt[I_E1], 1);
      if (p < E1CAP) { e1s[p] = s; e1d[p] = v; }
      mark_append(s, mark0, map0, s0list, &cnt[I_S0], S0CAP);
    }
  }
}

// xw1c[p] = x[s0list[p]] @ w1, persistent blocks over 32-row tiles
__global__ __launch_bounds__(256) void gemm1c_kernel(const float* __restrict__ x,
    const float* __restrict__ w, const int* __restrict__ s0list,
    const int* __restrict__ cnt, float* __restrict__ xw1c) {
  __shared__ float ws[F_IN * C];   // 32 KB
  __shared__ float xs[32 * F_IN];  // 16 KB
  int t = threadIdx.x;
  int s0c = cnt[I_S0]; if (s0c > S0CAP) s0c = S0CAP;
  for (int i = t; i < F_IN * C; i += 256) ws[i] = w[i];
  int ntile = (s0c + 31) / 32;
  for (int tile = blockIdx.x; tile < ntile; tile += gridDim.x) {
    __syncthreads();
    int r0 = tile * 32;
    for (int i = t; i < 32 * F_IN; i += 256) {
      int r = r0 + (i >> 7);
      xs[i] = (r < s0c) ? x[(size_t)s0list[r] * F_IN + (i & 127)] : 0.0f;
    }
    __syncthreads();
    int c = t & 63, rb = t >> 6;
    float acc[8];
#pragma unroll
    for (int j = 0; j < 8; ++j) acc[j] = 0.f;
    for (int k = 0; k < F_IN; ++k) {
      float wv = ws[k * C + c];
#pragma unroll
      for (int j = 0; j < 8; ++j)
        acc[j] += xs[(rb + j * 4) * F_IN + k] * wv;
    }
#pragma unroll
    for (int j = 0; j < 8; ++j) {
      int r = r0 + rb + j * 4;
      if (r < s0c) xw1c[(size_t)r * C + c] = acc[j];
    }
  }
}

// accumulate E1 edges into agg1c; wave per edge, lane = channel; dinv inline
__global__ __launch_bounds__(256) void gather1_kernel(const int* __restrict__ e1s,
    const int* __restrict__ e1d, const int* __restrict__ deg,
    const int* __restrict__ map0, const int* __restrict__ map1,
    const float* __restrict__ xw1c, float* __restrict__ agg1c,
    const int* __restrict__ cnt) {
  int n1 = cnt[I_E1]; if (n1 > E1CAP) n1 = E1CAP;
  int s0c = cnt[I_S0]; if (s0c > S0CAP) s0c = S0CAP;
  long total = (long)n1 * 64;
  long stride = (long)gridDim.x * 256;
  for (long i = (long)blockIdx.x * 256 + threadIdx.x; i < total; i += stride) {
    int e = (int)(i >> 6), c = (int)(i & 63);
    int s = e1s[e], d = e1d[e];
    int ms = map0[s];
    if ((unsigned)ms >= (unsigned)s0c) continue;  // cap-overflow guard
    float w = rsqrtf((float)deg[s] + 1.0f) * rsqrtf((float)deg[d] + 1.0f);
    atomicAdd(&agg1c[(size_t)map1[d] * C + c], w * xw1c[(size_t)ms * C + c]);
  }
}

// xw2c[q] = relu(agg1c[q] + self + b1) @ w2, persistent over 64-row tiles
__global__ __launch_bounds__(256) void gemm2c_kernel(const float* __restrict__ agg1c,
    const float* __restrict__ xw1c, const int* __restrict__ s1list,
    const int* __restrict__ map0, const int* __restrict__ deg,
    const float* __restrict__ b1, const float* __restrict__ w,
    float* __restrict__ xw2c, const int* __restrict__ cnt) {
  __shared__ float ws[C * C];   // 16 KB
  __shared__ float xs[64 * C];  // 16 KB
  int t = threadIdx.x;
  int sc = cnt[I_S1]; if (sc > S1CAP) sc = S1CAP;
  for (int i = t; i < C * C; i += 256) ws[i] = w[i];
  int ntile = (sc + 63) / 64;
  for (int tile = blockIdx.x; tile < ntile; tile += gridDim.x) {
    __syncthreads();
    int r0 = tile * 64;
    for (int i = t; i < 64 * C; i += 256) {
      int r = r0 + (i >> 6), cc = i & 63;
      float v = 0.0f;
      if (r < sc) {
        int nd = s1list[r];
        float dv = rsqrtf((float)deg[nd] + 1.0f);
        v = fmaxf(agg1c[(size_t)r * C + cc] +
                  xw1c[(size_t)map0[nd] * C + cc] * dv * dv + b1[cc], 0.0f);
      }
      xs[i] = v;
    }
    __syncthreads();
    int c = t & 63, rb = t >> 6;
    float acc[16];
#pragma unroll
    for (int j = 0; j < 16; ++j) acc[j] = 0.f;
    for (int k = 0; k < C; ++k) {
      float wv = ws[k * C + c];
#pragma unroll
      for (int j = 0; j < 16; ++j)
        acc[j] += xs[(rb + j * 4) * C + k] * wv;
    }
#pragma unroll
    for (int j = 0; j < 16; ++j) {
      int r = r0 + rb + j * 4;
      if (r < sc) xw2c[(size_t)r * C + c] = acc[j];
    }
  }
}

// single block: layer-2 aggregation of E2 into LDS + rank-ordered sigmoid readout
__global__ __launch_bounds__(1024) void readout_kernel(const int* __restrict__ src,
    const int* __restrict__ dst, const int* __restrict__ e2s,
    const int* __restrict__ e2d, const int* __restrict__ deg,
    const int* __restrict__ map1, const float* __restrict__ xw2c,
    const float* __restrict__ b2, const float* __restrict__ w_ro,
    const float* __restrict__ b_ro, const int* __restrict__ node_p,
    const int* __restrict__ elist, const int* __restrict__ cnt,
    int K, float* __restrict__ out) {
  __shared__ float aggL[ELCAP * C];  // 32 KB
  __shared__ int ids[ELCAP];
  int t = threadIdx.x;
  int tend = cnt[I_TEND]; if (tend > ELCAP) tend = ELCAP;
  int n = cnt[I_EL];
  if (n > K) n = K;
  if (n > ELCAP) n = ELCAP;
  for (int i = t; i < tend * C; i += 1024) aggL[i] = 0.0f;
  for (int i = t; i < n; i += 1024) ids[i] = elist[i];
  __syncthreads();
  // gather2 into LDS: wave per edge, lane = channel
  int n2 = cnt[I_E2]; if (n2 > E2CAP) n2 = E2CAP;
  int wid = t >> 6, lane = t & 63;
  for (int i = wid; i < n2; i += 16) {
    int s = e2s[i], d = e2d[i];
    int q = map1[d];
    if (q >= tend) continue;
    float w = rsqrtf((float)deg[s] + 1.0f) * rsqrtf((float)deg[d] + 1.0f);
    atomicAdd(&aggL[q * C + lane], w * xw2c[(size_t)map1[s] * C + lane]);
  }
  __syncthreads();
  int node = *node_p;
  for (int i = t; i < n; i += 1024) {
    int eid = ids[i];
    int rank = 0;
    for (int j = 0; j < n; ++j) rank += (ids[j] < eid) ? 1 : 0;
    int s = src[eid], d = dst[eid];
    int tgt = (s == node) ? d : s;
    int q = map1[tgt];
    float dv = rsqrtf((float)deg[tgt] + 1.0f);
    float acc = 0.f;
    for (int c2 = 0; c2 < C; ++c2) {
      float h = aggL[q * C + c2] + xw2c[(size_t)q * C + c2] * dv * dv + b2[c2];
      acc += fmaxf(h, 0.f) * w_ro[c2];
    }
    acc += b_ro[0];
    out[rank] = 1.0f / (1.0f + expf(-acc));
    out[K + rank] = (float)tgt;
  }
}

extern "C" void kernel_launch(void* const* d_in, const int* in_sizes, int n_in,
                              void* d_out, int out_size, void* d_ws, size_t ws_size,
                              hipStream_t stream) {
  const float* x    = (const float*)d_in[0];
  const int*   ei   = (const int*)d_in[1];
  const int*   node = (const int*)d_in[3];
  const float* w1   = (const float*)d_in[5];
  const float* b1   = (const float*)d_in[6];
  const float* w2   = (const float*)d_in[7];
  const float* b2   = (const float*)d_in[8];
  const float* w_ro = (const float*)d_in[9];
  const float* b_ro = (const float*)d_in[10];
  float* out = (float*)d_out;

  int nE = in_sizes[1] / 2;
  int nN = in_sizes[0] / F_IN;
  const int* src = ei;
  const int* dst = ei + nE;
  int K = out_size / 2;

  // ws layout (4-byte units); [deg|mark0|mark1|cnt|agg1c] contiguous for one memset
  int*   deg    = (int*)d_ws;
  int*   mark0  = deg + nN;
  int*   mark1  = mark0 + nN;
  int*   cnt    = mark1 + nN;
  float* agg1c  = (float*)(cnt + 16);
  int*   map0   = (int*)(agg1c + (size_t)S1CAP * C);
  int*   map1   = map0 + nN;
  int*   bucket = map1 + nN;
  int*   elist  = bucket + (size_t)nN * BCAP;
  int*   s0list = elist + ELCAP;
  int*   s1list = s0list + S0CAP;
  int*   e2s    = s1list + S1CAP;
  int*   e2d    = e2s + E2CAP;
  int*   e1s    = e2d + E2CAP;
  int*   e1d    = e1s + E1CAP;
  float* xw1c   = (float*)(e1d + E1CAP);
  float* xw2c   = xw1c + (size_t)S0CAP * C;

  hipMemsetAsync(deg, 0, ((size_t)3 * nN + 16 + (size_t)S1CAP * C) * 4, stream);

  maskfill_kernel<<<(nE + 255) / 256, 256, 0, stream>>>(src, dst, node, deg, bucket,
                                                        elist, cnt, nE);
  frontier12_kernel<<<1, 1024, 0, stream>>>(src, dst, node, elist, deg, bucket,
                                            mark0, mark1, map0, map1, s0list, s1list,
                                            e2s, e2d, cnt);
  frontier3_kernel<<<256, 256, 0, stream>>>(deg, bucket, s1list, mark0, map0, s0list,
                                            e1s, e1d, cnt);
  gemm1c_kernel<<<256, 256, 0, stream>>>(x, w1, s0list, cnt, xw1c);
  gather1_kernel<<<512, 256, 0, stream>>>(e1s, e1d, deg, map0, map1, xw1c, agg1c, cnt);
  gemm2c_kernel<<<16, 256, 0, stream>>>(agg1c, xw1c, s1list, map0, deg, b1, w2, xw2c, cnt);
  readout_kernel<<<1, 1024, 0, stream>>>(src, dst, e2s, e2d, deg, map1, xw2c, b2,
                                         w_ro, b_ro, node, elist, cnt, K, out);
}